// Round 1
// baseline (1778.986 us; speedup 1.0000x reference)
//
#include <hip/hip_runtime.h>
#include <math.h>

#define NS 4096
#define NV 65536
#define DDIM 128
#define EPSV 1e-6f
#define NCHUNK 16
#define CHUNK_NV (NV / NCHUNK)   // 4096 V rows per block
#define BM 128
#define BN 128
#define BK 16
#define LROW (BM + 8)            // 136 floats: keeps float4 16B-aligned, 2-way banks only
#define NT_PER (CHUNK_NV / BN)   // 32 tiles per block
#define FLTMAX 3.402823466e+38f

// ws layout (floats):
// [0,NV) v_sq | [NV,2NV) v_sum | [2NV,2NV+NS) x_sq | [2NV+NS,2NV+2NS) x_sum
// then float4 partials[NS*NCHUNK]  (d1, d2, i1, i2)  ~1 MB
// total ~1.6 MB of d_ws

__device__ __forceinline__ void merge2(float& d1, int& i1, float& d2, int& i2,
                                       float d, int i) {
    // top-2 with numpy top_k tie semantics: equal value -> lower index first
    bool b1 = (d < d1) || (d == d1 && i < i1);
    bool b2 = (d < d2) || (d == d2 && i < i2);
    if (b1) { d2 = d1; i2 = i1; d1 = d; i1 = i; }
    else if (b2 && i != i1) { d2 = d; i2 = i; }
}

__global__ void vq_precompute(const float* __restrict__ samples,
                              const float* __restrict__ V,
                              float* __restrict__ ws) {
    const int wave = threadIdx.x >> 6;
    const int lane = threadIdx.x & 63;
    int row = blockIdx.x * 4 + wave;
    const float* src; float* sqo; float* sumo; int r;
    if (row < NV) {
        r = row; src = V + (size_t)r * DDIM; sqo = ws; sumo = ws + NV;
    } else {
        r = row - NV;
        if (r >= NS) return;
        src = samples + (size_t)r * DDIM; sqo = ws + 2 * NV; sumo = ws + 2 * NV + NS;
    }
    float2 v = ((const float2*)src)[lane];   // 64 lanes x 2 floats = 128
    float s = v.x + v.y;
    float q = v.x * v.x + v.y * v.y;
    #pragma unroll
    for (int off = 32; off >= 1; off >>= 1) {
        s += __shfl_xor(s, off);
        q += __shfl_xor(q, off);
    }
    if (lane == 0) { sqo[r] = q; sumo[r] = s; }
}

__global__ __launch_bounds__(256, 2)
void vq_dist_topk(const float* __restrict__ samples, const float* __restrict__ V,
                  float* __restrict__ ws) {
    __shared__ float As[BK][LROW];
    __shared__ float Bs[BK][LROW];
    const int tid = threadIdx.x;
    const int tx = tid & 15;          // V-column group
    const int ty = tid >> 4;          // sample-row group
    const int chunk = blockIdx.x;     // which 4096-row V chunk
    const int m0 = blockIdx.y * BM;
    const int nbase = chunk * CHUNK_NV;
    const float* v_sq  = ws;
    const float* v_sum = ws + NV;
    const float* x_sq  = ws + 2 * NV;
    const float* x_sum = ws + 2 * NV + NS;
    float4* partials = (float4*)(ws + 2 * NV + 2 * NS);

    int mrow[8];
    float ci[8];
    #pragma unroll
    for (int i = 0; i < 8; i++) {
        int ml = (i < 4) ? (ty * 4 + i) : (64 + ty * 4 + (i - 4));
        int m = m0 + ml;
        mrow[i] = m;
        ci[i] = x_sq[m] + 2.0f * EPSV * x_sum[m] + (float)DDIM * EPSV * EPSV;
    }
    float d1[8], d2[8];
    int i1[8], i2[8];
    #pragma unroll
    for (int i = 0; i < 8; i++) {
        d1[i] = FLTMAX; d2[i] = FLTMAX; i1[i] = 0x7fffffff; i2[i] = 0x7fffffff;
    }

    for (int nt = 0; nt < NT_PER; nt++) {
        const int n0 = nbase + nt * BN;
        float acc[8][8];
        #pragma unroll
        for (int i = 0; i < 8; i++)
            #pragma unroll
            for (int j = 0; j < 8; j++) acc[i][j] = 0.0f;

        for (int kt = 0; kt < DDIM / BK; kt++) {
            const int k0 = kt * BK;
            #pragma unroll
            for (int i = 0; i < 2; i++) {
                int f4 = tid + i * 256;       // 0..511
                int r  = f4 >> 2;             // row 0..127 (both tiles 128 rows)
                int c4 = f4 & 3;              // which float4 within the 16-float K-chunk
                float4 av = *(const float4*)(samples + (size_t)(m0 + r) * DDIM + k0 + c4 * 4);
                float4 bv = *(const float4*)(V + (size_t)(n0 + r) * DDIM + k0 + c4 * 4);
                As[c4 * 4 + 0][r] = av.x;
                As[c4 * 4 + 1][r] = av.y;
                As[c4 * 4 + 2][r] = av.z;
                As[c4 * 4 + 3][r] = av.w;
                Bs[c4 * 4 + 0][r] = bv.x;
                Bs[c4 * 4 + 1][r] = bv.y;
                Bs[c4 * 4 + 2][r] = bv.z;
                Bs[c4 * 4 + 3][r] = bv.w;
            }
            __syncthreads();
            #pragma unroll
            for (int d = 0; d < BK; d++) {
                float4 a0 = *(const float4*)&As[d][ty * 4];
                float4 a1 = *(const float4*)&As[d][64 + ty * 4];
                float4 b0 = *(const float4*)&Bs[d][tx * 4];
                float4 b1 = *(const float4*)&Bs[d][64 + tx * 4];
                float a[8] = {a0.x, a0.y, a0.z, a0.w, a1.x, a1.y, a1.z, a1.w};
                float b[8] = {b0.x, b0.y, b0.z, b0.w, b1.x, b1.y, b1.z, b1.w};
                #pragma unroll
                for (int i = 0; i < 8; i++)
                    #pragma unroll
                    for (int j = 0; j < 8; j++)
                        acc[i][j] = fmaf(a[i], b[j], acc[i][j]);
            }
            __syncthreads();
        }
        // epilogue: distances + top-2 update (compare on rounded fp32 dist like the ref)
        #pragma unroll
        for (int j = 0; j < 8; j++) {
            int nl = (j < 4) ? (tx * 4 + j) : (64 + tx * 4 + (j - 4));
            int n = n0 + nl;
            float cj = v_sq[n] - 2.0f * EPSV * v_sum[n];
            #pragma unroll
            for (int i = 0; i < 8; i++) {
                float sq = ci[i] + cj - 2.0f * acc[i][j];
                float dist = sqrtf(fmaxf(sq, 0.0f));
                merge2(d1[i], i1[i], d2[i], i2[i], dist, n);
            }
        }
    }
    // reduce across the 16 tx lanes that share each sample row (same wave)
    #pragma unroll
    for (int off = 1; off < 16; off <<= 1) {
        #pragma unroll
        for (int i = 0; i < 8; i++) {
            float od1 = __shfl_xor(d1[i], off);
            int   oi1 = __shfl_xor(i1[i], off);
            float od2 = __shfl_xor(d2[i], off);
            int   oi2 = __shfl_xor(i2[i], off);
            merge2(d1[i], i1[i], d2[i], i2[i], od1, oi1);
            merge2(d1[i], i1[i], d2[i], i2[i], od2, oi2);
        }
    }
    if (tx == 0) {
        #pragma unroll
        for (int i = 0; i < 8; i++) {
            partials[(size_t)mrow[i] * NCHUNK + chunk] =
                make_float4(d1[i], d2[i], (float)i1[i], (float)i2[i]);
        }
    }
}

__global__ void vq_reduce(const float* __restrict__ ws, float* __restrict__ out) {
    int m = blockIdx.x * blockDim.x + threadIdx.x;
    if (m >= NS) return;
    const float4* partials = (const float4*)(ws + 2 * NV + 2 * NS);
    float d1 = FLTMAX, d2 = FLTMAX;
    int i1 = 0x7fffffff, i2 = 0x7fffffff;
    for (int c = 0; c < NCHUNK; c++) {   // ascending chunk order keeps tie-break = lowest idx
        float4 p = partials[(size_t)m * NCHUNK + c];
        merge2(d1, i1, d2, i2, p.x, (int)p.z);
        merge2(d1, i1, d2, i2, p.y, (int)p.w);
    }
    out[m]          = (float)i1;   // b
    out[NS + m]     = (float)i2;   // s
    out[2 * NS + m] = expf(-d1);   // a = exp(-nearest dist)
}

extern "C" void kernel_launch(void* const* d_in, const int* in_sizes, int n_in,
                              void* d_out, int out_size, void* d_ws, size_t ws_size,
                              hipStream_t stream) {
    (void)in_sizes; (void)n_in; (void)out_size; (void)ws_size;
    const float* samples = (const float*)d_in[0];
    const float* V = (const float*)d_in[1];
    float* out = (float*)d_out;
    float* ws = (float*)d_ws;

    vq_precompute<<<dim3((NV + NS) / 4), 256, 0, stream>>>(samples, V, ws);
    vq_dist_topk<<<dim3(NCHUNK, NS / BM), 256, 0, stream>>>(samples, V, ws);
    vq_reduce<<<dim3(NS / 256), 256, 0, stream>>>(ws, out);
}

// Round 2
// 299.147 us; speedup vs baseline: 5.9469x; 5.9469x over previous
//
#include <hip/hip_runtime.h>
#include <math.h>

#define NS 4096
#define NV 65536
#define DDIM 128
#define EPSV 1e-6f
#define NCHUNK 16
#define TILES_PER_CHUNK 32
#define FLTMAX 3.402823466e+38f
#define IMAX 0x7fffffff

// ws float offsets
#define VSQ_F   0
#define VSUM_F  65536
#define XSQ_F   131072
#define XSUM_F  135168
#define PART_F  139264              // 4096 samples x 16 chunks x float4
// tiled V region (bytes): starts right after floats end (401408*4), 256B aligned
#define WS_TILED_BYTE 1605632
#define TILE_BYTES 65536            // 8 s x 2 split x 2 q x 128 m x 16B
#define TILE_STRIDE 66560           // + 1KB cj slot (512B cj + pad)

typedef __attribute__((ext_vector_type(8)))  __bf16        bf16x8;
typedef __attribute__((ext_vector_type(8)))  unsigned short ush8;
typedef __attribute__((ext_vector_type(4)))  unsigned short ush4;
typedef __attribute__((ext_vector_type(16))) float          f32x16;

typedef const __attribute__((address_space(1))) unsigned int* gp_t;
typedef __attribute__((address_space(3))) unsigned int*       lp_t;

__device__ __forceinline__ void async_cp16(const void* g, void* l) {
    __builtin_amdgcn_global_load_lds((gp_t)g, (lp_t)l, 16, 0, 0);
}

__device__ __forceinline__ unsigned short f2bf(float x) {
    unsigned u = __builtin_bit_cast(unsigned, x);
    u += 0x7FFFu + ((u >> 16) & 1u);      // RNE
    return (unsigned short)(u >> 16);
}
__device__ __forceinline__ float bf2f(unsigned short h) {
    unsigned u = ((unsigned)h) << 16;
    return __builtin_bit_cast(float, u);
}

__device__ __forceinline__ void merge2t(float& d1, int& i1, float& d2, int& i2,
                                        float d, int i) {
    bool b1 = (d < d1) || (d == d1 && i < i1);
    bool b2 = (d < d2) || (d == d2 && i < i2);
    if (b1) { d2 = d1; i2 = i1; d1 = d; i1 = i; }
    else if (b2) { d2 = d; i2 = i; }
}

// ---- K1: row stats (v_sq, v_sum, x_sq, x_sum) ----
__global__ void vq_precompute(const float* __restrict__ samples,
                              const float* __restrict__ V,
                              float* __restrict__ ws) {
    const int wave = threadIdx.x >> 6;
    const int lane = threadIdx.x & 63;
    int row = blockIdx.x * 4 + wave;
    const float* src; float* sqo; float* sumo; int r;
    if (row < NV) {
        r = row; src = V + (size_t)r * DDIM; sqo = ws + VSQ_F; sumo = ws + VSUM_F;
    } else {
        r = row - NV;
        if (r >= NS) return;
        src = samples + (size_t)r * DDIM; sqo = ws + XSQ_F; sumo = ws + XSUM_F;
    }
    float2 v = ((const float2*)src)[lane];
    float s = v.x + v.y;
    float q = v.x * v.x + v.y * v.y;
    #pragma unroll
    for (int off = 32; off >= 1; off >>= 1) {
        s += __shfl_xor(s, off);
        q += __shfl_xor(q, off);
    }
    if (lane == 0) { sqo[r] = q; sumo[r] = s; }
}

// ---- K2: cj per code, written into its tile's cj slot ----
__global__ void vq_cj(const float* __restrict__ ws_f, char* __restrict__ ws) {
    int c = blockIdx.x * 256 + threadIdx.x;
    float cj = ws_f[VSQ_F + c] - 2.0f * EPSV * ws_f[VSUM_F + c];
    int tile = c >> 7, m = c & 127;
    *(float*)(ws + WS_TILED_BYTE + (size_t)tile * TILE_STRIDE + TILE_BYTES + m * 4) = cj;
}

// ---- K3: convert V -> tiled bf16 hi/lo fragments ----
__global__ void vq_convertV(const float* __restrict__ V, char* __restrict__ ws) {
    const int tile = blockIdx.x;
    const int tid = threadIdx.x;
    char* dst = ws + WS_TILED_BYTE + (size_t)tile * TILE_STRIDE;
    const float4* v4 = (const float4*)V;
    #pragma unroll
    for (int i = 0; i < 16; i++) {
        int flat = i * 256 + tid;           // 0..4095 float4s of the 128x128 tile
        int row = flat >> 5;
        int kq  = flat & 31;
        float4 g = v4[(size_t)(tile * 128 + row) * 32 + kq];
        int k0 = kq * 4;
        int s = k0 >> 4, q = (k0 >> 3) & 1, j0 = k0 & 7;   // j0 in {0,4}
        float xs[4] = {g.x, g.y, g.z, g.w};
        ush4 h, l;
        #pragma unroll
        for (int e = 0; e < 4; e++) {
            unsigned short hh = f2bf(xs[e]);
            h[e] = hh;
            l[e] = f2bf(xs[e] - bf2f(hh));
        }
        *(ush4*)(dst + ((((s * 2 + 0) * 2 + q) * 128) + row) * 16 + j0 * 2) = h;
        *(ush4*)(dst + ((((s * 2 + 1) * 2 + q) * 128) + row) * 16 + j0 * 2) = l;
    }
}

// ---- K4: MFMA GEMM + fused top-2 ----
// block: 256 thr = 4 waves; block tile: 128 codes (M) x 128 samples (N)
// wave w: all 128 codes x samples [w*32, w*32+32)
__global__ __launch_bounds__(256, 2)
void vq_gemm_topk(const float* __restrict__ samples, char* __restrict__ ws) {
    __shared__ __align__(16) char lds[TILE_STRIDE];
    const int tid = threadIdx.x;
    const int w = tid >> 6, lane = tid & 63;
    const int l31 = lane & 31, q = lane >> 5;
    const int st = blockIdx.x;       // sample tile 0..31
    const int chunk = blockIdx.y;    // 0..15
    const int nrow = st * 128 + w * 32 + l31;   // this lane's sample row

    // B fragments: samples scaled by -2 (exact), split hi/lo, held in VGPRs
    ush8 bh[8], bl[8];
    const float4* s4 = (const float4*)samples;
    #pragma unroll
    for (int s = 0; s < 8; s++) {
        float4 x0 = s4[(size_t)nrow * 32 + s * 4 + q * 2];
        float4 x1 = s4[(size_t)nrow * 32 + s * 4 + q * 2 + 1];
        float xs[8] = {x0.x, x0.y, x0.z, x0.w, x1.x, x1.y, x1.z, x1.w};
        #pragma unroll
        for (int j = 0; j < 8; j++) {
            float y = -2.0f * xs[j];
            unsigned short hh = f2bf(y);
            bh[s][j] = hh;
            bl[s][j] = f2bf(y - bf2f(hh));
        }
    }

    float d1 = FLTMAX, d2 = FLTMAX;
    int i1 = IMAX, i2 = IMAX;

    const char* tile0 = ws + WS_TILED_BYTE + (size_t)(chunk * TILES_PER_CHUNK) * TILE_STRIDE;

    for (int it = 0; it < TILES_PER_CHUNK; it++) {
        const char* src = tile0 + (size_t)it * TILE_STRIDE;
        #pragma unroll
        for (int i = 0; i < 16; i++) {
            int off = (i * 256 + tid) * 16;
            async_cp16(src + off, lds + off);
        }
        if (tid < 64) {
            int off = TILE_BYTES + tid * 16;   // cj slot (512B cj + 512B pad)
            async_cp16(src + off, lds + off);
        }
        __syncthreads();

        f32x16 acc[4];
        #pragma unroll
        for (int mi = 0; mi < 4; mi++)
            #pragma unroll
            for (int r = 0; r < 16; r++) acc[mi][r] = 0.0f;

        #pragma unroll
        for (int s = 0; s < 8; s++) {
            bf16x8 bhs = __builtin_bit_cast(bf16x8, bh[s]);
            bf16x8 bls = __builtin_bit_cast(bf16x8, bl[s]);
            #pragma unroll
            for (int mi = 0; mi < 4; mi++) {
                bf16x8 ah = *(const bf16x8*)(lds + (size_t)((((s * 2 + 0) * 2 + q) * 128) + mi * 32 + l31) * 16);
                bf16x8 al = *(const bf16x8*)(lds + (size_t)((((s * 2 + 1) * 2 + q) * 128) + mi * 32 + l31) * 16);
                acc[mi] = __builtin_amdgcn_mfma_f32_32x32x16_bf16(ah, bhs, acc[mi], 0, 0, 0);
                acc[mi] = __builtin_amdgcn_mfma_f32_32x32x16_bf16(ah, bls, acc[mi], 0, 0, 0);
                acc[mi] = __builtin_amdgcn_mfma_f32_32x32x16_bf16(al, bhs, acc[mi], 0, 0, 0);
            }
        }

        // epilogue: t = cj - 2*dot ; running top-2 per sample (this lane's column)
        const int cbase = chunk * 4096 + it * 128 + 4 * q;
        #pragma unroll
        for (int mi = 0; mi < 4; mi++) {
            #pragma unroll
            for (int g = 0; g < 4; g++) {
                float4 cj = *(const float4*)(lds + TILE_BYTES + (size_t)(mi * 32 + g * 8 + 4 * q) * 4);
                float cje[4] = {cj.x, cj.y, cj.z, cj.w};
                #pragma unroll
                for (int e = 0; e < 4; e++) {
                    float v = acc[mi][g * 4 + e] + cje[e];
                    int idx = cbase + mi * 32 + g * 8 + e;
                    bool c1 = v < d1, c2 = v < d2;
                    float nd2 = c1 ? d1 : v;
                    int   ni2 = c1 ? i1 : idx;
                    d2 = c2 ? nd2 : d2;
                    i2 = c2 ? ni2 : i2;
                    d1 = c1 ? v : d1;
                    i1 = c1 ? idx : i1;
                }
            }
        }
        __syncthreads();
    }

    // merge the two lanes (q=0,1) holding the same sample; q=0 has lower codes,
    // strict < keeps lower index on exact ties for the q==0 writer
    {
        float od1 = __shfl_xor(d1, 32), od2 = __shfl_xor(d2, 32);
        int   oi1 = __shfl_xor(i1, 32), oi2 = __shfl_xor(i2, 32);
        merge2t(d1, i1, d2, i2, od1, oi1);
        merge2t(d1, i1, d2, i2, od2, oi2);
    }
    if (q == 0) {
        int sample = st * 128 + w * 32 + l31;
        float4* part = (float4*)( (float*)((char*)ws) + PART_F );
        part[(size_t)sample * NCHUNK + chunk] = make_float4(d1, d2, (float)i1, (float)i2);
    }
}

// ---- K5: merge chunk partials, final outputs ----
__global__ void vq_reduce(const float* __restrict__ ws_f, float* __restrict__ out) {
    int m = blockIdx.x * 256 + threadIdx.x;
    if (m >= NS) return;
    const float4* part = (const float4*)(ws_f + PART_F);
    float d1 = FLTMAX, d2 = FLTMAX;
    int i1 = IMAX, i2 = IMAX;
    for (int c = 0; c < NCHUNK; c++) {
        float4 p = part[(size_t)m * NCHUNK + c];
        merge2t(d1, i1, d2, i2, p.x, (int)p.z);
        merge2t(d1, i1, d2, i2, p.y, (int)p.w);
    }
    float ci = ws_f[XSQ_F + m] + 2.0f * EPSV * ws_f[XSUM_F + m] + (float)DDIM * EPSV * EPSV;
    float sq = fmaxf(ci + d1, 0.0f);
    out[m]          = (float)i1;
    out[NS + m]     = (float)i2;
    out[2 * NS + m] = expf(-sqrtf(sq));
}

extern "C" void kernel_launch(void* const* d_in, const int* in_sizes, int n_in,
                              void* d_out, int out_size, void* d_ws, size_t ws_size,
                              hipStream_t stream) {
    (void)in_sizes; (void)n_in; (void)out_size; (void)ws_size;
    const float* samples = (const float*)d_in[0];
    const float* V = (const float*)d_in[1];
    float* out = (float*)d_out;
    float* ws_f = (float*)d_ws;
    char*  ws_b = (char*)d_ws;

    vq_precompute<<<dim3((NV + NS) / 4), 256, 0, stream>>>(samples, V, ws_f);
    vq_cj<<<dim3(NV / 256), 256, 0, stream>>>(ws_f, ws_b);
    vq_convertV<<<dim3(NV / 128), 256, 0, stream>>>(V, ws_b);
    vq_gemm_topk<<<dim3(NS / 128, NCHUNK), 256, 0, stream>>>(samples, ws_b);
    vq_reduce<<<dim3(NS / 256), 256, 0, stream>>>(ws_f, out);
}